// Round 2
// baseline (371.106 us; speedup 1.0000x reference)
//
#include <hip/hip_runtime.h>

// ---------------------------------------------------------------------------
// TransVLAD fused pipeline for MI355X (gfx950)
// Shapes: N=32, C=512, H=W=32 (P=1024), E=1024, G=8, D=128, K=64
// out: [N, K*D] fp32 (262144)
//
// R2 fix: agg_part was allocated 8 MB but needs 16 MB -> K4 agg writes
// clobbered wsum_part (error signature: absmax ~= max|wsum*centroids| ~= 64).
// Also shrank att partials (full-E sum in K3, [N][G][P], 1 MB) to cut total
// workspace to ~114.8 MB.
// ---------------------------------------------------------------------------

#define N_  32
#define C_  512
#define P_  1024
#define E_  1024
#define G_  8
#define D_  128
#define K_  64

typedef __attribute__((ext_vector_type(8))) short bf16x8;
typedef __attribute__((ext_vector_type(4))) float f32x4;

__device__ __forceinline__ unsigned short f2b(float f) {
    union { float f; unsigned u; } v; v.f = f;
    unsigned r = (v.u + 0x7FFFu + ((v.u >> 16) & 1u)) >> 16;
    return (unsigned short)r;
}
__device__ __forceinline__ float b2f(unsigned short h) {
    union { unsigned u; float f; } v; v.u = ((unsigned)h) << 16;
    return v.f;
}

// ---------------------------------------------------------------------------
// K0a: convert W1 [E,C] fp32 -> bf16
__global__ __launch_bounds__(256) void k0a_convert_w1(const float* __restrict__ W1,
                                                      unsigned short* __restrict__ W1b) {
    int i = blockIdx.x * 256 + threadIdx.x;   // grid 2048 -> 524288 exactly
    W1b[i] = f2b(W1[i]);
}

// K0b: V[g][k][c] = sum_d Wc[k][d] * W1[g*128+d][c]  -> bf16 Vb [G*K, C]
// grid 1024: bid = ((g*64)+k)*2 + ch ; thread c = ch*256 + t
__global__ __launch_bounds__(256) void k0b_make_v(const float* __restrict__ W1,
                                                  const float* __restrict__ Wc,
                                                  unsigned short* __restrict__ Vb) {
    int bid = blockIdx.x;
    int ch = bid & 1, k = (bid >> 1) & 63, g = bid >> 7;
    int c = ch * 256 + threadIdx.x;
    float acc = 0.f;
    #pragma unroll 8
    for (int d = 0; d < 128; ++d) {
        acc += Wc[k * 128 + d] * W1[(g * 128 + d) * C_ + c];
    }
    Vb[(g * 64 + k) * C_ + c] = f2b(acc);
}

// ---------------------------------------------------------------------------
// K1: per-pixel L2 norm over C, write x_hat transposed: xhat_t [N][P][C] bf16
// grid (16,32): p0 = bx*64, n = by.  256 threads.
__global__ __launch_bounds__(256) void k1_norm_transpose(const float* __restrict__ x,
                                                         unsigned short* __restrict__ xhat_t) {
    __shared__ float rn[64];
    __shared__ float tile[64 * 65];
    int n = blockIdx.y;
    int p0 = blockIdx.x * 64;
    int t = threadIdx.x;
    int ps = t & 63, cs = t >> 6;   // cs in 0..3

    // phase A: sum of squares (each (cs,ps) covers c in [cs*128, cs*128+128))
    float ss = 0.f;
    for (int i = 0; i < 128; ++i) {
        int c = cs * 128 + i;
        float v = x[(n * C_ + c) * P_ + p0 + ps];
        ss += v * v;
    }
    tile[t] = ss;
    __syncthreads();
    if (t < 64) {
        float s = tile[t] + tile[64 + t] + tile[128 + t] + tile[192 + t];
        rn[t] = 1.0f / fmaxf(sqrtf(s), 1e-12f);
    }
    __syncthreads();

    // phase B: transpose 64c x 64p tiles through LDS, scale, write bf16
    for (int cb = 0; cb < C_; cb += 64) {
        #pragma unroll
        for (int i = 0; i < 16; ++i) {
            int cl = (t >> 6) * 16 + i;           // 0..63
            tile[cl * 65 + (t & 63)] = x[(n * C_ + cb + cl) * P_ + p0 + (t & 63)];
        }
        __syncthreads();
        #pragma unroll
        for (int pr = 0; pr < 16; ++pr) {
            int ps2 = (t >> 6) * 16 + pr;         // pixel 0..63
            int cl2 = t & 63;                     // channel-local
            float v = tile[cl2 * 65 + ps2] * rn[ps2];
            xhat_t[((size_t)(n * P_ + p0 + ps2)) * C_ + cb + cl2] = f2b(v);
        }
        __syncthreads();
    }
}

// ---------------------------------------------------------------------------
// K2: xe[n][e][p] = sum_c W1b[e][c] * xhat_t[n][p][c]   (bf16 MFMA GEMM, NT)
// grid (64, 32): e0 = (bx>>3)*128, p0 = (bx&7)*128, n = by. 256 thr = 4 waves.
__global__ __launch_bounds__(256) void k2_gemm_xe(const unsigned short* __restrict__ W1b,
                                                  const unsigned short* __restrict__ xhat_t,
                                                  unsigned short* __restrict__ xe) {
    __shared__ __align__(16) short As[128 * 32];
    __shared__ __align__(16) short Bs[128 * 32];
    int n = blockIdx.y;
    int e0 = (blockIdx.x >> 3) * 128;
    int p0 = (blockIdx.x & 7) * 128;
    int t = threadIdx.x;
    int w = t >> 6, l = t & 63, q = l >> 4, l15 = l & 15;
    int wr = w >> 1, wc = w & 1;   // wave quadrant in 128x128

    f32x4 acc[4][4];
    #pragma unroll
    for (int mi = 0; mi < 4; ++mi)
        #pragma unroll
        for (int ni = 0; ni < 4; ++ni)
            acc[mi][ni] = (f32x4){0.f, 0.f, 0.f, 0.f};

    for (int ks = 0; ks < 16; ++ks) {
        int k0 = ks * 32;
        // stage A tile: W1b rows e0..e0+127, cols k0..k0+31  ([128][32] row-major)
        #pragma unroll
        for (int i = 0; i < 2; ++i) {
            int ch = i * 256 + t;                   // 16B chunk id
            int row = ch >> 2, col = (ch & 3) * 8;
            *(int4*)&As[ch * 8] = *(const int4*)&W1b[(e0 + row) * C_ + k0 + col];
        }
        // stage B tile: xhat_t rows p0..p0+127, cols k0..k0+31
        #pragma unroll
        for (int i = 0; i < 2; ++i) {
            int ch = i * 256 + t;
            int row = ch >> 2, col = (ch & 3) * 8;
            *(int4*)&Bs[ch * 8] = *(const int4*)&xhat_t[((size_t)(n * P_ + p0 + row)) * C_ + k0 + col];
        }
        __syncthreads();

        bf16x8 af[4], bf[4];
        #pragma unroll
        for (int mi = 0; mi < 4; ++mi)
            af[mi] = *(const bf16x8*)&As[(wr * 64 + mi * 16 + l15) * 32 + q * 8];
        #pragma unroll
        for (int ni = 0; ni < 4; ++ni)
            bf[ni] = *(const bf16x8*)&Bs[(wc * 64 + ni * 16 + l15) * 32 + q * 8];
        #pragma unroll
        for (int mi = 0; mi < 4; ++mi)
            #pragma unroll
            for (int ni = 0; ni < 4; ++ni)
                acc[mi][ni] = __builtin_amdgcn_mfma_f32_16x16x32_bf16(af[mi], bf[ni], acc[mi][ni], 0, 0, 0);
        __syncthreads();
    }

    // epilogue: C/D layout col=l&15, row=q*4+r
    #pragma unroll
    for (int mi = 0; mi < 4; ++mi) {
        #pragma unroll
        for (int ni = 0; ni < 4; ++ni) {
            #pragma unroll
            for (int r = 0; r < 4; ++r) {
                int e = e0 + wr * 64 + mi * 16 + q * 4 + r;
                int p = p0 + wc * 64 + ni * 16 + l15;
                xe[((size_t)(n * E_ + e)) * P_ + p] = f2b(acc[mi][ni][r]);
            }
        }
    }
}

// ---------------------------------------------------------------------------
// K3: attention logits: att[n][g][p] = sum_e xe[e][p]*W2[g][e]   (full E sum)
// grid (4, 32): p = bx*256 + t, n = by.
__global__ __launch_bounds__(256) void k3_att(const unsigned short* __restrict__ xe,
                                              const float* __restrict__ W2,
                                              float* __restrict__ att) {
    int n = blockIdx.y;
    int p = blockIdx.x * 256 + threadIdx.x;
    float acc[8];
    #pragma unroll
    for (int g = 0; g < 8; ++g) acc[g] = 0.f;
    for (int e = 0; e < E_; ++e) {
        float v = b2f(xe[((size_t)(n * E_ + e)) * P_ + p]);
        #pragma unroll
        for (int g = 0; g < 8; ++g)
            acc[g] += v * W2[g * E_ + e];      // W2 read is wave-uniform (scalar)
    }
    #pragma unroll
    for (int g = 0; g < 8; ++g)
        att[(((size_t)(n * G_ + g)) * P_) + p] = acc[g];
}

// ---------------------------------------------------------------------------
// K4: fused assignment -> softmax -> gate -> aggregation per (n, g, ph)
// grid (16, 32): g = bx&7, ph = bx>>3, n = by. 256 thr = 4 waves.
// S[k][p] = sum_c Vb[g][k][c]*xhat_t[p][c];  softmax over k;  *= sigmoid(att)
// agg[k][d] += sum_p w[k][p]*xe[g*128+d][p];   wsum[k] += sum_p w[k][p]
__global__ __launch_bounds__(256) void k4_assign_agg(const unsigned short* __restrict__ Vb,
                                                     const unsigned short* __restrict__ xhat_t,
                                                     const unsigned short* __restrict__ xe,
                                                     const float* __restrict__ att,
                                                     float* __restrict__ agg_part,
                                                     float* __restrict__ wsum_part) {
    __shared__ __align__(16) short As2[64 * 32];      // Vb tile
    __shared__ __align__(16) short Bs2[128 * 32];     // xhat tile
    __shared__ __align__(16) short wlds[64 * 136];    // w, k-major (A-layout for agg)
    __shared__ __align__(16) short xglds[128 * 136];  // xg, d-major (B-layout for agg)

    int g = blockIdx.x & 7, ph = blockIdx.x >> 3, n = blockIdx.y;
    int t = threadIdx.x;
    int w = t >> 6, l = t & 63, q = l >> 4, l15 = l & 15;

    f32x4 acc_a[4][2];
    #pragma unroll
    for (int mi = 0; mi < 4; ++mi)
        #pragma unroll
        for (int ni = 0; ni < 2; ++ni)
            acc_a[mi][ni] = (f32x4){0.f, 0.f, 0.f, 0.f};
    float wsp[16];
    #pragma unroll
    for (int j = 0; j < 16; ++j) wsp[j] = 0.f;

    for (int cc = 0; cc < 4; ++cc) {
        int p0c = ph * 512 + cc * 128;    // pixel base within image

        // ---- Phase S: S = Vb[g] (64xC) * xhat^T (Cx128) ----
        f32x4 acc_s[4][2];
        #pragma unroll
        for (int mi = 0; mi < 4; ++mi)
            #pragma unroll
            for (int ni = 0; ni < 2; ++ni)
                acc_s[mi][ni] = (f32x4){0.f, 0.f, 0.f, 0.f};

        for (int ks = 0; ks < 16; ++ks) {
            int k0 = ks * 32;
            {   // As2: 64x32, 256 chunks, 1 per thread
                int row = t >> 2, col = (t & 3) * 8;
                *(int4*)&As2[t * 8] = *(const int4*)&Vb[(g * 64 + row) * C_ + k0 + col];
            }
            #pragma unroll
            for (int i = 0; i < 2; ++i) {   // Bs2: 128x32
                int ch = i * 256 + t;
                int row = ch >> 2, col = (ch & 3) * 8;
                *(int4*)&Bs2[ch * 8] = *(const int4*)&xhat_t[((size_t)(n * P_ + p0c + row)) * C_ + k0 + col];
            }
            __syncthreads();
            bf16x8 af[4], bf2[2];
            #pragma unroll
            for (int mi = 0; mi < 4; ++mi)
                af[mi] = *(const bf16x8*)&As2[(mi * 16 + l15) * 32 + q * 8];
            #pragma unroll
            for (int ni = 0; ni < 2; ++ni)
                bf2[ni] = *(const bf16x8*)&Bs2[(w * 32 + ni * 16 + l15) * 32 + q * 8];
            #pragma unroll
            for (int mi = 0; mi < 4; ++mi)
                #pragma unroll
                for (int ni = 0; ni < 2; ++ni)
                    acc_s[mi][ni] = __builtin_amdgcn_mfma_f32_16x16x32_bf16(af[mi], bf2[ni], acc_s[mi][ni], 0, 0, 0);
            __syncthreads();
        }

        // ---- softmax over k (64 values live in 4 quad-lanes x 16 regs) ----
        #pragma unroll
        for (int ni = 0; ni < 2; ++ni) {
            float m = -1e30f;
            #pragma unroll
            for (int mi = 0; mi < 4; ++mi)
                #pragma unroll
                for (int r = 0; r < 4; ++r)
                    m = fmaxf(m, acc_s[mi][ni][r]);
            m = fmaxf(m, __shfl_xor(m, 16));
            m = fmaxf(m, __shfl_xor(m, 32));
            float s = 0.f;
            #pragma unroll
            for (int mi = 0; mi < 4; ++mi)
                #pragma unroll
                for (int r = 0; r < 4; ++r) {
                    float e = __expf(acc_s[mi][ni][r] - m);
                    acc_s[mi][ni][r] = e;
                    s += e;
                }
            s += __shfl_xor(s, 16);
            s += __shfl_xor(s, 32);

            int pcol = p0c + w * 32 + ni * 16 + l15;   // pixel in image
            float av = att[(((size_t)(n * G_ + g)) * P_) + pcol];
            av = 1.0f / (1.0f + __expf(-av));          // sigmoid
            float scale = av / s;

            #pragma unroll
            for (int mi = 0; mi < 4; ++mi)
                #pragma unroll
                for (int r = 0; r < 4; ++r) {
                    float wv = acc_s[mi][ni][r] * scale;
                    wsp[mi * 4 + r] += wv;
                    wlds[(mi * 16 + q * 4 + r) * 136 + (w * 32 + ni * 16 + l15)] = (short)f2b(wv);
                }
        }

        // ---- stage xg (d-major): xglds[d][p], rows e = g*128+d, cols p0c.. ----
        // 128*136 shorts = 2176 16B-chunks: 8 full rounds + half round
        #pragma unroll
        for (int i = 0; i < 8; ++i) {
            int ch = i * 256 + t;
            int row = ch / 17, col = (ch % 17) * 8;
            *(int4*)&xglds[ch * 8] = *(const int4*)&xe[((size_t)(n * E_ + g * 128 + row)) * P_ + p0c + col];
        }
        if (t < 128) {
            int ch = 2048 + t;
            int row = ch / 17, col = (ch % 17) * 8;
            *(int4*)&xglds[ch * 8] = *(const int4*)&xe[((size_t)(n * E_ + g * 128 + row)) * P_ + p0c + col];
        }
        __syncthreads();

        // ---- agg MFMA: A = w [64k x 128p], B = xg [128d x 128p] (NT) ----
        #pragma unroll
        for (int pk = 0; pk < 4; ++pk) {
            bf16x8 a2[4], b2[2];
            #pragma unroll
            for (int mi = 0; mi < 4; ++mi)
                a2[mi] = *(const bf16x8*)&wlds[(mi * 16 + l15) * 136 + pk * 32 + q * 8];
            #pragma unroll
            for (int ni = 0; ni < 2; ++ni)
                b2[ni] = *(const bf16x8*)&xglds[(w * 32 + ni * 16 + l15) * 136 + pk * 32 + q * 8];
            #pragma unroll
            for (int mi = 0; mi < 4; ++mi)
                #pragma unroll
                for (int ni = 0; ni < 2; ++ni)
                    acc_a[mi][ni] = __builtin_amdgcn_mfma_f32_16x16x32_bf16(a2[mi], b2[ni], acc_a[mi][ni], 0, 0, 0);
        }
        __syncthreads();
    }

    // ---- epilogue: agg partials [n][g][ph][k][d] ----
    size_t base = (((size_t)(n * G_ + g)) * 2 + ph) * 64;
    #pragma unroll
    for (int mi = 0; mi < 4; ++mi)
        #pragma unroll
        for (int ni = 0; ni < 2; ++ni)
            #pragma unroll
            for (int r = 0; r < 4; ++r) {
                int k = mi * 16 + q * 4 + r;
                int d = w * 32 + ni * 16 + l15;
                agg_part[(base + k) * 128 + d] = acc_a[mi][ni][r];
            }

    // ---- wsum partials [n][g][ph][w][k] (reduce over the 16 pixel-lanes) ----
    #pragma unroll
    for (int j = 0; j < 16; ++j) {
        float v = wsp[j];
        v += __shfl_xor(v, 1);
        v += __shfl_xor(v, 2);
        v += __shfl_xor(v, 4);
        v += __shfl_xor(v, 8);
        if (l15 == 0) {
            int k = (j >> 2) * 16 + q * 4 + (j & 3);
            wsum_part[((((size_t)(n * G_ + g)) * 2 + ph) * 4 + w) * 64 + k] = v;
        }
    }
}

// ---------------------------------------------------------------------------
// K5: vlad[n][k][d] = sum_{g,ph} agg_part - (sum_{g,ph,w} wsum_part)*centroids[k][d]
__global__ __launch_bounds__(256) void k5_final(const float* __restrict__ agg_part,
                                                const float* __restrict__ wsum_part,
                                                const float* __restrict__ centroids,
                                                float* __restrict__ out) {
    int idx = blockIdx.x * 256 + threadIdx.x;   // grid 1024 -> 262144 exactly
    int d = idx & 127;
    int k = (idx >> 7) & 63;
    int n = idx >> 13;
    float ws = 0.f;
    #pragma unroll
    for (int g = 0; g < 8; ++g)
        #pragma unroll
        for (int ph = 0; ph < 2; ++ph)
            #pragma unroll
            for (int w2 = 0; w2 < 4; ++w2)
                ws += wsum_part[((((size_t)(n * G_ + g)) * 2 + ph) * 4 + w2) * 64 + k];
    float agg = 0.f;
    #pragma unroll
    for (int g = 0; g < 8; ++g)
        #pragma unroll
        for (int ph = 0; ph < 2; ++ph)
            agg += agg_part[(((((size_t)(n * G_ + g)) * 2 + ph) * 64) + k) * 128 + d];
    out[idx] = agg - ws * centroids[k * 128 + d];
}

// ---------------------------------------------------------------------------
extern "C" void kernel_launch(void* const* d_in, const int* in_sizes, int n_in,
                              void* d_out, int out_size, void* d_ws, size_t ws_size,
                              hipStream_t stream) {
    const float* x         = (const float*)d_in[0];   // [32,512,32,32]
    const float* W1        = (const float*)d_in[1];   // [1024,512]
    const float* W2        = (const float*)d_in[2];   // [8,1024]
    const float* Wc        = (const float*)d_in[3];   // [64,128]
    const float* centroids = (const float*)d_in[4];   // [64,128]
    float* out = (float*)d_out;                       // [32, 8192]

    // Workspace layout (sizes EXACT this time):
    //   W1b      [E*C]           bf16   1,048,576 B  @ 0
    //   Vb       [G*K*C]         bf16     524,288 B  @ 1,048,576
    //   xhat_t   [N*P*C]         bf16  33,554,432 B  @ 1,572,864
    //   xe       [N*E*P]         bf16  67,108,864 B  @ 35,127,296
    //   att      [N*G*P]         f32    1,048,576 B  @ 102,236,160
    //   agg_part [N*G*2*K*D]     f32   16,777,216 B  @ 103,284,736
    //   wsum_part[N*G*2*4*K]     f32      262,144 B  @ 120,061,952
    //   total: 120,324,096 B (~114.8 MB)
    char* ws = (char*)d_ws;
    unsigned short* W1b      = (unsigned short*)(ws + 0);
    unsigned short* Vb       = (unsigned short*)(ws + 1048576);
    unsigned short* xhat_t   = (unsigned short*)(ws + 1572864);
    unsigned short* xe       = (unsigned short*)(ws + 35127296);
    float*          att      = (float*)(ws + 102236160);
    float*          agg_part = (float*)(ws + 103284736);
    float*          wsum_part= (float*)(ws + 120061952);

    hipLaunchKernelGGL(k0a_convert_w1, dim3(2048), dim3(256), 0, stream, W1, W1b);
    hipLaunchKernelGGL(k0b_make_v,     dim3(1024), dim3(256), 0, stream, W1, Wc, Vb);
    hipLaunchKernelGGL(k1_norm_transpose, dim3(16, 32), dim3(256), 0, stream, x, xhat_t);
    hipLaunchKernelGGL(k2_gemm_xe,     dim3(64, 32), dim3(256), 0, stream, W1b, xhat_t, xe);
    hipLaunchKernelGGL(k3_att,         dim3(4, 32), dim3(256), 0, stream, xe, W2, att);
    hipLaunchKernelGGL(k4_assign_agg,  dim3(16, 32), dim3(256), 0, stream, Vb, xhat_t, xe,
                       att, agg_part, wsum_part);
    hipLaunchKernelGGL(k5_final,       dim3(1024), dim3(256), 0, stream,
                       agg_part, wsum_part, centroids, out);
}

// Round 3
// 262.733 us; speedup vs baseline: 1.4125x; 1.4125x over previous
//
#include <hip/hip_runtime.h>

// ---------------------------------------------------------------------------
// TransVLAD fused pipeline for MI355X (gfx950)
// Shapes: N=32, C=512, H=W=32 (P=1024), E=1024, G=8, D=128, K=64
// out: [N, K*D] fp32 (262144)
//
// R3: (a) k3 was 103us @ 5.6% occupancy (128 blocks) -> split into k3a
// partials (2048 blocks, coalesced) + k3b reduce w/ fused sigmoid.
// (b) global_load_lds width=16 async staging in K2/K4 (m97 pattern).
// att_part (16MB) aliases agg_part (dead until K4 writes).
// ---------------------------------------------------------------------------

#define N_  32
#define C_  512
#define P_  1024
#define E_  1024
#define G_  8
#define D_  128
#define K_  64

typedef __attribute__((ext_vector_type(8))) short bf16x8;
typedef __attribute__((ext_vector_type(4))) float f32x4;

__device__ __forceinline__ unsigned short f2b(float f) {
    union { float f; unsigned u; } v; v.f = f;
    unsigned r = (v.u + 0x7FFFu + ((v.u >> 16) & 1u)) >> 16;
    return (unsigned short)r;
}
__device__ __forceinline__ float b2f(unsigned short h) {
    union { unsigned u; float f; } v; v.u = ((unsigned)h) << 16;
    return v.f;
}

// async global->LDS 16B copy: LDS dest must be wave-uniform base + lane*16
__device__ __forceinline__ void gl_lds16(const void* g, void* l) {
    __builtin_amdgcn_global_load_lds(
        (const __attribute__((address_space(1))) void*)g,
        (__attribute__((address_space(3))) void*)l, 16, 0, 0);
}

// ---------------------------------------------------------------------------
// K0a: convert W1 [E,C] fp32 -> bf16
__global__ __launch_bounds__(256) void k0a_convert_w1(const float* __restrict__ W1,
                                                      unsigned short* __restrict__ W1b) {
    int i = blockIdx.x * 256 + threadIdx.x;   // grid 2048 -> 524288 exactly
    W1b[i] = f2b(W1[i]);
}

// K0b: V[g][k][c] = sum_d Wc[k][d] * W1[g*128+d][c]  -> bf16 Vb [G*K, C]
__global__ __launch_bounds__(256) void k0b_make_v(const float* __restrict__ W1,
                                                  const float* __restrict__ Wc,
                                                  unsigned short* __restrict__ Vb) {
    int bid = blockIdx.x;
    int ch = bid & 1, k = (bid >> 1) & 63, g = bid >> 7;
    int c = ch * 256 + threadIdx.x;
    float acc = 0.f;
    #pragma unroll 8
    for (int d = 0; d < 128; ++d) {
        acc += Wc[k * 128 + d] * W1[(g * 128 + d) * C_ + c];
    }
    Vb[(g * 64 + k) * C_ + c] = f2b(acc);
}

// ---------------------------------------------------------------------------
// K1: per-pixel L2 norm over C, write x_hat transposed: xhat_t [N][P][C] bf16
__global__ __launch_bounds__(256) void k1_norm_transpose(const float* __restrict__ x,
                                                         unsigned short* __restrict__ xhat_t) {
    __shared__ float rn[64];
    __shared__ float tile[64 * 65];
    int n = blockIdx.y;
    int p0 = blockIdx.x * 64;
    int t = threadIdx.x;
    int ps = t & 63, cs = t >> 6;   // cs in 0..3

    float ss = 0.f;
    for (int i = 0; i < 128; ++i) {
        int c = cs * 128 + i;
        float v = x[(n * C_ + c) * P_ + p0 + ps];
        ss += v * v;
    }
    tile[t] = ss;
    __syncthreads();
    if (t < 64) {
        float s = tile[t] + tile[64 + t] + tile[128 + t] + tile[192 + t];
        rn[t] = 1.0f / fmaxf(sqrtf(s), 1e-12f);
    }
    __syncthreads();

    for (int cb = 0; cb < C_; cb += 64) {
        #pragma unroll
        for (int i = 0; i < 16; ++i) {
            int cl = (t >> 6) * 16 + i;
            tile[cl * 65 + (t & 63)] = x[(n * C_ + cb + cl) * P_ + p0 + (t & 63)];
        }
        __syncthreads();
        #pragma unroll
        for (int pr = 0; pr < 16; ++pr) {
            int ps2 = (t >> 6) * 16 + pr;
            int cl2 = t & 63;
            float v = tile[cl2 * 65 + ps2] * rn[ps2];
            xhat_t[((size_t)(n * P_ + p0 + ps2)) * C_ + cb + cl2] = f2b(v);
        }
        __syncthreads();
    }
}

// ---------------------------------------------------------------------------
// K2: xe[n][e][p] = sum_c W1b[e][c] * xhat_t[n][p][c]   (bf16 MFMA GEMM, NT)
// grid (64, 32): e0 = (bx>>3)*128, p0 = (bx&7)*128, n = by. 256 thr = 4 waves.
__global__ __launch_bounds__(256) void k2_gemm_xe(const unsigned short* __restrict__ W1b,
                                                  const unsigned short* __restrict__ xhat_t,
                                                  unsigned short* __restrict__ xe) {
    __shared__ __align__(16) short As[128 * 32];
    __shared__ __align__(16) short Bs[128 * 32];
    int n = blockIdx.y;
    int e0 = (blockIdx.x >> 3) * 128;
    int p0 = (blockIdx.x & 7) * 128;
    int t = threadIdx.x;
    int w = t >> 6, l = t & 63, q = l >> 4, l15 = l & 15;
    int wr = w >> 1, wc = w & 1;

    f32x4 acc[4][4];
    #pragma unroll
    for (int mi = 0; mi < 4; ++mi)
        #pragma unroll
        for (int ni = 0; ni < 4; ++ni)
            acc[mi][ni] = (f32x4){0.f, 0.f, 0.f, 0.f};

    for (int ks = 0; ks < 16; ++ks) {
        int k0 = ks * 32;
        // async stage A/B tiles (16B per lane; LDS addr = wave base + lane*16)
        #pragma unroll
        for (int i = 0; i < 2; ++i) {
            int ch = i * 256 + t;
            int row = ch >> 2, col = (ch & 3) * 8;
            gl_lds16(&W1b[(e0 + row) * C_ + k0 + col], &As[ch * 8]);
        }
        #pragma unroll
        for (int i = 0; i < 2; ++i) {
            int ch = i * 256 + t;
            int row = ch >> 2, col = (ch & 3) * 8;
            gl_lds16(&xhat_t[((size_t)(n * P_ + p0 + row)) * C_ + k0 + col], &Bs[ch * 8]);
        }
        __syncthreads();

        bf16x8 af[4], bf[4];
        #pragma unroll
        for (int mi = 0; mi < 4; ++mi)
            af[mi] = *(const bf16x8*)&As[(wr * 64 + mi * 16 + l15) * 32 + q * 8];
        #pragma unroll
        for (int ni = 0; ni < 4; ++ni)
            bf[ni] = *(const bf16x8*)&Bs[(wc * 64 + ni * 16 + l15) * 32 + q * 8];
        #pragma unroll
        for (int mi = 0; mi < 4; ++mi)
            #pragma unroll
            for (int ni = 0; ni < 4; ++ni)
                acc[mi][ni] = __builtin_amdgcn_mfma_f32_16x16x32_bf16(af[mi], bf[ni], acc[mi][ni], 0, 0, 0);
        __syncthreads();
    }

    #pragma unroll
    for (int mi = 0; mi < 4; ++mi) {
        #pragma unroll
        for (int ni = 0; ni < 4; ++ni) {
            #pragma unroll
            for (int r = 0; r < 4; ++r) {
                int e = e0 + wr * 64 + mi * 16 + q * 4 + r;
                int p = p0 + wc * 64 + ni * 16 + l15;
                xe[((size_t)(n * E_ + e)) * P_ + p] = f2b(acc[mi][ni][r]);
            }
        }
    }
}

// ---------------------------------------------------------------------------
// K3a: att partials over 64-wide e-chunks.
// grid (64, 32): pblk = bx&3, ec = bx>>2 (0..15); n = by. p = pblk*256 + t.
// att_part[n][ec][g][p] = sum_{e in chunk} xe[e][p] * W2[g][e]
__global__ __launch_bounds__(256) void k3a_att_part(const unsigned short* __restrict__ xe,
                                                    const float* __restrict__ W2,
                                                    float* __restrict__ att_part) {
    int n = blockIdx.y;
    int pblk = blockIdx.x & 3, ec = blockIdx.x >> 2;
    int p = pblk * 256 + threadIdx.x;
    int e0 = ec * 64;
    float acc[8];
    #pragma unroll
    for (int g = 0; g < 8; ++g) acc[g] = 0.f;
    #pragma unroll 8
    for (int i = 0; i < 64; ++i) {
        int e = e0 + i;
        float v = b2f(xe[((size_t)(n * E_ + e)) * P_ + p]);   // 128B/wave, coalesced
        #pragma unroll
        for (int g = 0; g < 8; ++g)
            acc[g] += v * W2[g * E_ + e];                      // wave-uniform s_load
    }
    #pragma unroll
    for (int g = 0; g < 8; ++g)
        att_part[(((size_t)(n * 16 + ec)) * 8 + g) * P_ + p] = acc[g];
}

// K3b: att_s[n][g][p] = sigmoid( sum_ec att_part[n][ec][g][p] )
__global__ __launch_bounds__(256) void k3b_att_reduce(const float* __restrict__ att_part,
                                                      float* __restrict__ att_s) {
    int idx = blockIdx.x * 256 + threadIdx.x;   // grid 1024 -> 262144 exactly
    int p = idx & 1023;
    int g = (idx >> 10) & 7;
    int n = idx >> 13;
    float s = 0.f;
    #pragma unroll
    for (int ec = 0; ec < 16; ++ec)
        s += att_part[(((size_t)(n * 16 + ec)) * 8 + g) * P_ + p];
    att_s[idx] = 1.0f / (1.0f + __expf(-s));
}

// ---------------------------------------------------------------------------
// K4: fused assignment -> softmax -> gate -> aggregation per (n, g, ph)
// grid (16, 32): g = bx&7, ph = bx>>3, n = by. 256 thr = 4 waves.
__global__ __launch_bounds__(256) void k4_assign_agg(const unsigned short* __restrict__ Vb,
                                                     const unsigned short* __restrict__ xhat_t,
                                                     const unsigned short* __restrict__ xe,
                                                     const float* __restrict__ att_s,
                                                     float* __restrict__ agg_part,
                                                     float* __restrict__ wsum_part) {
    __shared__ __align__(16) short As2[64 * 32];      // Vb tile
    __shared__ __align__(16) short Bs2[128 * 32];     // xhat tile
    __shared__ __align__(16) short wlds[64 * 136];    // w, k-major (A-layout for agg)
    __shared__ __align__(16) short xglds[128 * 136];  // xg, d-major (B-layout for agg)

    int g = blockIdx.x & 7, ph = blockIdx.x >> 3, n = blockIdx.y;
    int t = threadIdx.x;
    int w = t >> 6, l = t & 63, q = l >> 4, l15 = l & 15;

    f32x4 acc_a[4][2];
    #pragma unroll
    for (int mi = 0; mi < 4; ++mi)
        #pragma unroll
        for (int ni = 0; ni < 2; ++ni)
            acc_a[mi][ni] = (f32x4){0.f, 0.f, 0.f, 0.f};
    float wsp[16];
    #pragma unroll
    for (int j = 0; j < 16; ++j) wsp[j] = 0.f;

    for (int cc = 0; cc < 4; ++cc) {
        int p0c = ph * 512 + cc * 128;

        // ---- Phase S: S = Vb[g] (64xC) * xhat^T (Cx128) ----
        f32x4 acc_s[4][2];
        #pragma unroll
        for (int mi = 0; mi < 4; ++mi)
            #pragma unroll
            for (int ni = 0; ni < 2; ++ni)
                acc_s[mi][ni] = (f32x4){0.f, 0.f, 0.f, 0.f};

        for (int ks = 0; ks < 16; ++ks) {
            int k0 = ks * 32;
            {   // As2: 64x32, 1 chunk/thread
                int row = t >> 2, col = (t & 3) * 8;
                gl_lds16(&Vb[(g * 64 + row) * C_ + k0 + col], &As2[t * 8]);
            }
            #pragma unroll
            for (int i = 0; i < 2; ++i) {   // Bs2: 128x32
                int ch = i * 256 + t;
                int row = ch >> 2, col = (ch & 3) * 8;
                gl_lds16(&xhat_t[((size_t)(n * P_ + p0c + row)) * C_ + k0 + col], &Bs2[ch * 8]);
            }
            __syncthreads();
            bf16x8 af[4], bf2[2];
            #pragma unroll
            for (int mi = 0; mi < 4; ++mi)
                af[mi] = *(const bf16x8*)&As2[(mi * 16 + l15) * 32 + q * 8];
            #pragma unroll
            for (int ni = 0; ni < 2; ++ni)
                bf2[ni] = *(const bf16x8*)&Bs2[(w * 32 + ni * 16 + l15) * 32 + q * 8];
            #pragma unroll
            for (int mi = 0; mi < 4; ++mi)
                #pragma unroll
                for (int ni = 0; ni < 2; ++ni)
                    acc_s[mi][ni] = __builtin_amdgcn_mfma_f32_16x16x32_bf16(af[mi], bf2[ni], acc_s[mi][ni], 0, 0, 0);
            __syncthreads();
        }

        // ---- softmax over k + gate ----
        #pragma unroll
        for (int ni = 0; ni < 2; ++ni) {
            float m = -1e30f;
            #pragma unroll
            for (int mi = 0; mi < 4; ++mi)
                #pragma unroll
                for (int r = 0; r < 4; ++r)
                    m = fmaxf(m, acc_s[mi][ni][r]);
            m = fmaxf(m, __shfl_xor(m, 16));
            m = fmaxf(m, __shfl_xor(m, 32));
            float s = 0.f;
            #pragma unroll
            for (int mi = 0; mi < 4; ++mi)
                #pragma unroll
                for (int r = 0; r < 4; ++r) {
                    float e = __expf(acc_s[mi][ni][r] - m);
                    acc_s[mi][ni][r] = e;
                    s += e;
                }
            s += __shfl_xor(s, 16);
            s += __shfl_xor(s, 32);

            int pcol = p0c + w * 32 + ni * 16 + l15;
            float av = att_s[(((size_t)(n * G_ + g)) * P_) + pcol];  // pre-sigmoided
            float scale = av / s;

            #pragma unroll
            for (int mi = 0; mi < 4; ++mi)
                #pragma unroll
                for (int r = 0; r < 4; ++r) {
                    float wv = acc_s[mi][ni][r] * scale;
                    wsp[mi * 4 + r] += wv;
                    wlds[(mi * 16 + q * 4 + r) * 136 + (w * 32 + ni * 16 + l15)] = (short)f2b(wv);
                }
        }

        // ---- stage xg (d-major) async: 2176 chunks = 8 rounds + half ----
        #pragma unroll
        for (int i = 0; i < 8; ++i) {
            int ch = i * 256 + t;
            int row = ch / 17, col = (ch % 17) * 8;
            gl_lds16(&xe[((size_t)(n * E_ + g * 128 + row)) * P_ + p0c + col], &xglds[ch * 8]);
        }
        if (t < 128) {
            int ch = 2048 + t;
            int row = ch / 17, col = (ch % 17) * 8;
            gl_lds16(&xe[((size_t)(n * E_ + g * 128 + row)) * P_ + p0c + col], &xglds[ch * 8]);
        }
        __syncthreads();

        // ---- agg MFMA: A = w [64k x 128p], B = xg [128d x 128p] (NT) ----
        #pragma unroll
        for (int pk = 0; pk < 4; ++pk) {
            bf16x8 a2[4], b2[2];
            #pragma unroll
            for (int mi = 0; mi < 4; ++mi)
                a2[mi] = *(const bf16x8*)&wlds[(mi * 16 + l15) * 136 + pk * 32 + q * 8];
            #pragma unroll
            for (int ni = 0; ni < 2; ++ni)
                b2[ni] = *(const bf16x8*)&xglds[(w * 32 + ni * 16 + l15) * 136 + pk * 32 + q * 8];
            #pragma unroll
            for (int mi = 0; mi < 4; ++mi)
                #pragma unroll
                for (int ni = 0; ni < 2; ++ni)
                    acc_a[mi][ni] = __builtin_amdgcn_mfma_f32_16x16x32_bf16(a2[mi], b2[ni], acc_a[mi][ni], 0, 0, 0);
        }
        __syncthreads();
    }

    // ---- epilogue ----
    size_t base = (((size_t)(n * G_ + g)) * 2 + ph) * 64;
    #pragma unroll
    for (int mi = 0; mi < 4; ++mi)
        #pragma unroll
        for (int ni = 0; ni < 2; ++ni)
            #pragma unroll
            for (int r = 0; r < 4; ++r) {
                int k = mi * 16 + q * 4 + r;
                int d = w * 32 + ni * 16 + l15;
                agg_part[(base + k) * 128 + d] = acc_a[mi][ni][r];
            }

    #pragma unroll
    for (int j = 0; j < 16; ++j) {
        float v = wsp[j];
        v += __shfl_xor(v, 1);
        v += __shfl_xor(v, 2);
        v += __shfl_xor(v, 4);
        v += __shfl_xor(v, 8);
        if (l15 == 0) {
            int k = (j >> 2) * 16 + q * 4 + (j & 3);
            wsum_part[((((size_t)(n * G_ + g)) * 2 + ph) * 4 + w) * 64 + k] = v;
        }
    }
}

// ---------------------------------------------------------------------------
// K5: vlad[n][k][d] = sum_{g,ph} agg_part - (sum) * centroids
__global__ __launch_bounds__(256) void k5_final(const float* __restrict__ agg_part,
                                                const float* __restrict__ wsum_part,
                                                const float* __restrict__ centroids,
                                                float* __restrict__ out) {
    int idx = blockIdx.x * 256 + threadIdx.x;   // grid 1024 -> 262144 exactly
    int d = idx & 127;
    int k = (idx >> 7) & 63;
    int n = idx >> 13;
    float ws = 0.f;
    #pragma unroll
    for (int g = 0; g < 8; ++g)
        #pragma unroll
        for (int ph = 0; ph < 2; ++ph)
            #pragma unroll
            for (int w2 = 0; w2 < 4; ++w2)
                ws += wsum_part[((((size_t)(n * G_ + g)) * 2 + ph) * 4 + w2) * 64 + k];
    float agg = 0.f;
    #pragma unroll
    for (int g = 0; g < 8; ++g)
        #pragma unroll
        for (int ph = 0; ph < 2; ++ph)
            agg += agg_part[(((((size_t)(n * G_ + g)) * 2 + ph) * 64) + k) * 128 + d];
    out[idx] = agg - ws * centroids[k * 128 + d];
}

// ---------------------------------------------------------------------------
extern "C" void kernel_launch(void* const* d_in, const int* in_sizes, int n_in,
                              void* d_out, int out_size, void* d_ws, size_t ws_size,
                              hipStream_t stream) {
    const float* x         = (const float*)d_in[0];
    const float* W1        = (const float*)d_in[1];
    const float* W2        = (const float*)d_in[2];
    const float* Wc        = (const float*)d_in[3];
    const float* centroids = (const float*)d_in[4];
    float* out = (float*)d_out;

    // Workspace layout (total 120,324,096 B — same footprint as R2):
    //   W1b      [E*C]           bf16   1,048,576 B  @ 0
    //   Vb       [G*K*C]         bf16     524,288 B  @ 1,048,576
    //   xhat_t   [N*P*C]         bf16  33,554,432 B  @ 1,572,864
    //   xe       [N*E*P]         bf16  67,108,864 B  @ 35,127,296
    //   att_s    [N*G*P]         f32    1,048,576 B  @ 102,236,160
    //   agg_part [N*G*2*K*D]     f32   16,777,216 B  @ 103,284,736  (ALIASES att_part[N][16][G][P])
    //   wsum_part[N*G*2*4*K]     f32      262,144 B  @ 120,061,952
    char* ws = (char*)d_ws;
    unsigned short* W1b      = (unsigned short*)(ws + 0);
    unsigned short* Vb       = (unsigned short*)(ws + 1048576);
    unsigned short* xhat_t   = (unsigned short*)(ws + 1572864);
    unsigned short* xe       = (unsigned short*)(ws + 35127296);
    float*          att_s    = (float*)(ws + 102236160);
    float*          agg_part = (float*)(ws + 103284736);
    float*          att_part = (float*)(ws + 103284736);   // alias: dead before K4
    float*          wsum_part= (float*)(ws + 120061952);

    hipLaunchKernelGGL(k0a_convert_w1, dim3(2048), dim3(256), 0, stream, W1, W1b);
    hipLaunchKernelGGL(k0b_make_v,     dim3(1024), dim3(256), 0, stream, W1, Wc, Vb);
    hipLaunchKernelGGL(k1_norm_transpose, dim3(16, 32), dim3(256), 0, stream, x, xhat_t);
    hipLaunchKernelGGL(k2_gemm_xe,     dim3(64, 32), dim3(256), 0, stream, W1b, xhat_t, xe);
    hipLaunchKernelGGL(k3a_att_part,   dim3(64, 32), dim3(256), 0, stream, xe, W2, att_part);
    hipLaunchKernelGGL(k3b_att_reduce, dim3(1024), dim3(256), 0, stream, att_part, att_s);
    hipLaunchKernelGGL(k4_assign_agg,  dim3(16, 32), dim3(256), 0, stream, Vb, xhat_t, xe,
                       att_s, agg_part, wsum_part);
    hipLaunchKernelGGL(k5_final,       dim3(1024), dim3(256), 0, stream,
                       agg_part, wsum_part, centroids, out);
}